// Round 8
// baseline (6813.906 us; speedup 1.0000x reference)
//
#include <hip/hip_runtime.h>
#include <stdint.h>

// B=32, L=256, D=128. Reader LSTM scan + attention-memory writer scan.
// ALL inputs/outputs FP32.
// Round-8: empirical law from rounds 3-7: register-resident weight arrays
// spill (128-VGPR budget, 16MB scratch, +1.1ms); only Mr/Mc (AGPR-backed)
// survive. So stream ALL weights (bf16-packed), and attack stall time:
//  - gate-interleaved column permutation: slot s <-> col (s&3)*128+(s>>2);
//    gates of dim d live in one lane-quad -> 2x shfl_xor, no LDS trip.
//  - reader: 1 barrier/step (double-buffered h in LDS).
//  - writer: 7 barriers/step; Uw matvec ILP-mixed with m_rt partials (off
//    softmax critical path); c_t as 128-thread full dots; o_t prefetched
//    into non-reading phases.

#define LL 256
#define NT 512

typedef float v2f __attribute__((ext_vector_type(2)));

__device__ __forceinline__ float asf(uint32_t u) { union { uint32_t i; float f; } v; v.i = u; return v.f; }
__device__ __forceinline__ float lo2(uint32_t u) { return asf(u << 16); }
__device__ __forceinline__ float hi2(uint32_t u) { return asf(u & 0xffff0000u); }
__device__ __forceinline__ v2f bf2(uint32_t u) { v2f r; r.x = lo2(u); r.y = hi2(u); return r; }
__device__ __forceinline__ float bfu(unsigned short u) { return asf(((uint32_t)u) << 16); }
__device__ __forceinline__ uint32_t bfr(float x) {           // fp32 -> bf16 bits, RTNE
  union { float f; uint32_t i; } v; v.f = x;
  return (v.i + 0x7fffu + ((v.i >> 16) & 1u)) >> 16;
}
__device__ __forceinline__ uint32_t pack2(float a, float b) { return bfr(a) | (bfr(b) << 16); }
__device__ __forceinline__ float hsig(float x) { return fminf(fmaxf(fmaf(x, 0.2f, 0.5f), 0.f), 1.f); }
__device__ __forceinline__ float tanh_fast(float x) {
  x = fminf(fmaxf(x, -15.f), 15.f);
  float e = __expf(2.f * x);
  return (e - 1.f) / (e + 1.f);
}

// ---- Prep 1: XWb[(b*L+t)*512 + s] = bf16((x@Wr+br)[col perm(s)]) ---------
__global__ __launch_bounds__(512) void xw_kernel(const float* __restrict__ x,
                                                 const float* __restrict__ Wr,
                                                 const float* __restrict__ br,
                                                 unsigned short* __restrict__ XWb) {
  __shared__ float xr[1024];
  const int tid = threadIdx.x;
  const int jp = (tid & 3) * 128 + (tid >> 2);   // permuted column
  const size_t r0 = (size_t)blockIdx.x * 8;      // 8 (b,t) rows per block
  const float* xg = x + r0 * 128;
  xr[tid] = xg[tid];
  xr[tid + 512] = xg[tid + 512];
  __syncthreads();
  float acc[8];
  const float b0 = br[jp];
#pragma unroll
  for (int r = 0; r < 8; r++) acc[r] = b0;
  for (int k = 0; k < 128; k++) {
    float w = Wr[k * 512 + jp];
#pragma unroll
    for (int r = 0; r < 8; r++) acc[r] = fmaf(w, xr[r * 128 + k], acc[r]);
  }
#pragma unroll
  for (int r = 0; r < 8; r++)
    XWb[(r0 + r) * 512 + tid] = (unsigned short)bfr(acc[r]);
}

// ---- Prep 2: permuted pack of 128x512 W -> bf16-pair uint4 stream ---------
// u32 idx (i4*512+s)*4+c holds pack2(W[2p][j],W[2p+1][j]), p=i4*4+c,
// j = (s&3)*128 + (s>>2).
__global__ __launch_bounds__(512) void packWperm_kernel(const float* __restrict__ W,
                                                        uint32_t* __restrict__ out) {
  int idx = blockIdx.x * 512 + threadIdx.x;      // 32768
  int i4 = idx >> 11;
  int s  = (idx >> 2) & 511;
  int c  = idx & 3;
  int j  = (s & 3) * 128 + (s >> 2);
  int p  = i4 * 4 + c;
  out[idx] = pack2(W[(2 * p) * 512 + j], W[(2 * p + 1) * 512 + j]);
}

// ---- Prep 3: Wc(256x128) -> bf16-pair uint4, k-major for 128-thread dots --
// uint4 index kp4*128 + j, comp c: k0 = 8*kp4 + 2*c.
__global__ __launch_bounds__(512) void packWcJ_kernel(const float* __restrict__ Wc,
                                                      uint32_t* __restrict__ out) {
  int idx = blockIdx.x * 512 + threadIdx.x;      // 16384
  int kp4 = idx >> 9;
  int j = (idx >> 2) & 127;
  int c = idx & 3;
  int k0 = 8 * kp4 + 2 * c;
  out[idx] = pack2(Wc[k0 * 128 + j], Wc[(k0 + 1) * 128 + j]);
}

// ---- Fused sequential kernel ----------------------------------------------
__global__ __launch_bounds__(512) void fused_kernel(
    const float* __restrict__ x, const uint32_t* __restrict__ UrP,
    const uint32_t* __restrict__ WwP, const uint32_t* __restrict__ UwP,
    const uint32_t* __restrict__ WcJ, const unsigned short* __restrict__ XWb,
    const float* __restrict__ bw, const float* __restrict__ bc,
    uint32_t* __restrict__ og, float* __restrict__ out) {
  alignas(16) __shared__ float hr_s[2][128];     // reader h double buffer
  alignas(16) __shared__ float h_s[128];         // writer h
  alignas(16) __shared__ float osA[128], osB[128];
  alignas(16) __shared__ float sc_s[256], ee_s[256];
  alignas(16) __shared__ float mr_s[128], ct_s[128];
  alignas(16) __shared__ float pp_s[1024];
  __shared__ float rr_s[16];

  const int b = blockIdx.x, tid = threadIdx.x;
  const int lane = tid & 63, wv = tid >> 6;
  const int l = tid >> 1, hf = tid & 1;          // row-major mem role
  const int q = tid >> 6, dp = tid & 63;         // col-major mem role
  const int g4 = tid & 3, d4 = tid >> 2;         // gate-interleave role

  const unsigned short* xwb = XWb + (size_t)b * (LL * 512);
  uint32_t* ogb = og + (size_t)b * (LL * 64);
  const float bwj = bw[g4 * 128 + d4];           // permuted bias
  const float bcj = (tid < 128) ? bc[tid] : 0.f;

  const uint4* UrP4 = (const uint4*)UrP;
  const uint4* WwP4 = (const uint4*)WwP;
  const uint4* UwP4 = (const uint4*)UwP;
  const uint4* WcJ4 = (const uint4*)WcJ;

  // ================= READER: 1 barrier/step =================
  {
    float c_r = 0.f;
    if (tid < 128) hr_s[0][tid] = 0.f;
    __syncthreads();
    for (int t = 0; t < LL; t++) {
      const float* hc = hr_s[t & 1];
      float* hn_ = hr_s[(t + 1) & 1];
      float xwv = bfu(xwb[t * 512 + tid]);
      v2f A = {0.f, 0.f};
#pragma unroll
      for (int i4 = 0; i4 < 16; i4++) {
        uint4 uq = UrP4[i4 * 512 + tid];
        const v2f* hp = (const v2f*)&hc[8 * i4];
        A += bf2(uq.x) * hp[0];
        A += bf2(uq.y) * hp[1];
        A += bf2(uq.z) * hp[2];
        A += bf2(uq.w) * hp[3];
      }
      float z = A.x + A.y + xwv;
      float zq1 = __shfl_xor(z, 1);
      float zq2 = __shfl_xor(z, 2);
      float zq3 = __shfl_xor(zq1, 2);
      float h = 0.f;
      if (g4 == 0) {                             // lane owns dim d4
        float ii = hsig(z), ff = hsig(zq1), gg = tanh_fast(zq2), oo = hsig(zq3);
        c_r = fmaf(ff, c_r, ii * gg);
        h = oo * tanh_fast(c_r);
        hn_[d4] = h;
      }
      float hnb = __shfl_down(h, 4);             // h of dim d4+1 (valid on tid%8==0)
      if ((tid & 7) == 0) ogb[t * 64 + (d4 >> 1)] = pack2(h, hnb);
      __syncthreads();
    }
  }

  // ================= WRITER =================
  // mem (== x, untouched) -> registers, dual layout (ONLY resident arrays)
  const float* xg = x + (size_t)b * (LL * 128);
  v2f Mr[32], Mc[32];
#pragma unroll
  for (int w = 0; w < 32; w++) Mr[w] = *(const v2f*)(xg + l * 128 + hf * 64 + 2 * w);
#pragma unroll
  for (int i = 0; i < 32; i++) Mc[i] = *(const v2f*)(xg + (q * 32 + i) * 128 + 2 * dp);

  float c_w = 0.f;
  if (tid < 128) h_s[tid] = 0.f;
  if (tid < 64) { v2f o = bf2(ogb[tid]); osA[2 * tid] = o.x; osA[2 * tid + 1] = o.y; }
  else if (tid < 128) { v2f o = bf2(ogb[64 + (tid - 64)]); osB[2 * (tid - 64)] = o.x; osB[2 * (tid - 64) + 1] = o.y; }
  __syncthreads();
  { // prologue: sc_s[l] = mem0[l] . o_0
    v2f S = {0.f, 0.f};
#pragma unroll
    for (int w = 0; w < 32; w++) S += Mr[w] * (*(const v2f*)&osA[hf * 64 + 2 * w]);
    float s = S.x + S.y;
    s += __shfl_xor(s, 1);
    if (hf == 0) sc_s[l] = s;
  }
  __syncthreads();

  for (int t = 0; t < LL; t++) {
    // A: softmax max
    if (tid < 256) {
      float m = sc_s[tid];
#pragma unroll
      for (int off = 32; off > 0; off >>= 1) m = fmaxf(m, __shfl_xor(m, off));
      if (lane == 0) rr_s[wv] = m;
    }
    __syncthreads();
    // B: exp + sum
    if (tid < 256) {
      float mx = fmaxf(fmaxf(rr_s[0], rr_s[1]), fmaxf(rr_s[2], rr_s[3]));
      float e = __expf(sc_s[tid] - mx);
      ee_s[tid] = e;
      float s2 = e;
#pragma unroll
      for (int off = 32; off > 0; off >>= 1) s2 += __shfl_xor(s2, off);
      if (lane == 0) rr_s[8 + wv] = s2;
    }
    __syncthreads();
    const float inv = 1.f / (rr_s[8] + rr_s[9] + rr_s[10] + rr_s[11]);
    // C: m_rt partials (Mc regs, ee broadcast) + z4a = h@Uw (stream), ILP-mixed
    float z4a;
    {
      v2f P = {0.f, 0.f};
      v2f A = {0.f, 0.f};
#pragma unroll
      for (int i4 = 0; i4 < 16; i4++) {
        uint4 uq = UwP4[i4 * 512 + tid];
        const v2f* hp = (const v2f*)&h_s[8 * i4];
        A += bf2(uq.x) * hp[0];
        A += bf2(uq.y) * hp[1];
        A += bf2(uq.z) * hp[2];
        A += bf2(uq.w) * hp[3];
        P += Mc[2 * i4] * ee_s[q * 32 + 2 * i4];
        P += Mc[2 * i4 + 1] * ee_s[q * 32 + 2 * i4 + 1];
      }
      z4a = A.x + A.y;
      *(v2f*)&pp_s[q * 128 + 2 * dp] = P;
    }
    __syncthreads();
    // D: m_rt reduce
    if (tid < 128) {
      float s = 0.f;
#pragma unroll
      for (int g = 0; g < 8; g++) s += pp_s[g * 128 + tid];
      mr_s[tid] = s * inv;
    }
    __syncthreads();
    // E: c_t full dot per output j (128 threads)
    if (tid < 128) {
      v2f A = {0.f, 0.f};
#pragma unroll
      for (int kp4 = 0; kp4 < 16; kp4++) {       // k in [0,128): o_t
        uint4 wq = WcJ4[kp4 * 128 + tid];
        const v2f* vp = (const v2f*)&osA[8 * kp4];
        A += bf2(wq.x) * vp[0];
        A += bf2(wq.y) * vp[1];
        A += bf2(wq.z) * vp[2];
        A += bf2(wq.w) * vp[3];
      }
#pragma unroll
      for (int kp4 = 16; kp4 < 32; kp4++) {      // k in [128,256): m_rt
        uint4 wq = WcJ4[kp4 * 128 + tid];
        const v2f* vp = (const v2f*)&mr_s[8 * (kp4 - 16)];
        A += bf2(wq.x) * vp[0];
        A += bf2(wq.y) * vp[1];
        A += bf2(wq.z) * vp[2];
        A += bf2(wq.w) * vp[3];
      }
      ct_s[tid] = bcj + A.x + A.y;
    }
    __syncthreads();
    // F: z4b = ct@Ww (stream) + gates via quad-shuffle; prefetch osB<-o_{t+1}
    {
      v2f A = {0.f, 0.f};
#pragma unroll
      for (int i4 = 0; i4 < 16; i4++) {
        uint4 wq = WwP4[i4 * 512 + tid];
        const v2f* cp = (const v2f*)&ct_s[8 * i4];
        A += bf2(wq.x) * cp[0];
        A += bf2(wq.y) * cp[1];
        A += bf2(wq.z) * cp[2];
        A += bf2(wq.w) * cp[3];
      }
      float z = z4a + A.x + A.y + bwj;
      float zq1 = __shfl_xor(z, 1);
      float zq2 = __shfl_xor(z, 2);
      float zq3 = __shfl_xor(zq1, 2);
      if (g4 == 0) {
        float ii = hsig(z), ff = hsig(zq1), gg = tanh_fast(zq2), oo = hsig(zq3);
        c_w = fmaf(ff, c_w, ii * gg);
        h_s[d4] = oo * tanh_fast(c_w);
      }
      if (tid >= 64 && tid < 128 && t + 1 < LL) {
        int u = tid - 64;
        v2f o = bf2(ogb[(t + 1) * 64 + u]);
        osB[2 * u] = o.x; osB[2 * u + 1] = o.y;
      }
    }
    __syncthreads();
    // G: mem update (both layouts, identical math) + next scores (osB);
    //    prefetch osA<-o_{t+1} for next step's E
    if (t + 1 < LL) {
      const float zr = ee_s[l] * inv;
      v2f S = {0.f, 0.f};
#pragma unroll
      for (int w = 0; w < 32; w++) {
        v2f h2 = *(const v2f*)&h_s[hf * 64 + 2 * w];
        v2f m = Mr[w];
        v2f n = m + (h2 - m) * zr;
        Mr[w] = n;
        S += n * (*(const v2f*)&osB[hf * 64 + 2 * w]);
      }
      float s = S.x + S.y;
      s += __shfl_xor(s, 1);
      if (hf == 0) sc_s[l] = s;
      v2f hc = *(const v2f*)&h_s[2 * dp];
#pragma unroll
      for (int i = 0; i < 32; i++) {
        float zc = ee_s[q * 32 + i] * inv;
        v2f m = Mc[i];
        Mc[i] = m + (hc - m) * zc;
      }
      if (tid < 64) {
        v2f o = bf2(ogb[(t + 1) * 64 + tid]);
        osA[2 * tid] = o.x; osA[2 * tid + 1] = o.y;
      }
    }
    __syncthreads();
  }

  if (tid < 128) out[b * 128 + tid] = h_s[tid];
}

extern "C" void kernel_launch(void* const* d_in, const int* in_sizes, int n_in,
                              void* d_out, int out_size, void* d_ws, size_t ws_size,
                              hipStream_t stream) {
  const float* x  = (const float*)d_in[0];
  const float* Wr = (const float*)d_in[1];
  const float* Ur = (const float*)d_in[2];
  const float* br = (const float*)d_in[3];
  const float* Ww = (const float*)d_in[4];
  const float* Uw = (const float*)d_in[5];
  const float* bw = (const float*)d_in[6];
  const float* Wc = (const float*)d_in[7];
  const float* bc = (const float*)d_in[8];
  float* out = (float*)d_out;

  // ws (u32 units): og 524288 | XWb 2,097,152 (4.19M ushort) | UrP 32768 |
  // WwP 32768 | UwP 32768 | WcJ 16384  -> ~10.94 MB
  uint32_t* wsw = (uint32_t*)d_ws;
  uint32_t* og = wsw;
  unsigned short* XWb = (unsigned short*)(wsw + 524288);
  uint32_t* UrP = wsw + 524288 + 2097152;
  uint32_t* WwP = UrP + 32768;
  uint32_t* UwP = WwP + 32768;
  uint32_t* WcJ = UwP + 32768;

  xw_kernel<<<32 * LL / 8, 512, 0, stream>>>(x, Wr, br, XWb);
  packWperm_kernel<<<64, 512, 0, stream>>>(Ur, UrP);
  packWperm_kernel<<<64, 512, 0, stream>>>(Ww, WwP);
  packWperm_kernel<<<64, 512, 0, stream>>>(Uw, UwP);
  packWcJ_kernel<<<32, 512, 0, stream>>>(Wc, WcJ);
  fused_kernel<<<32, NT, 0, stream>>>(x, UrP, WwP, UwP, WcJ, XWb, bw, bc, og, out);
}